// Round 3
// baseline (141.086 us; speedup 1.0000x reference)
//
#include <hip/hip_runtime.h>
#include <math.h>

#define D_BINS 59
#define CO     64
#define CI     256
#define NB     4
#define NC     6
#define H_IMG  16
#define W_IMG  44
#define HW     704            // H_IMG * W_IMG
#define NPIX   (NB*NC*HW)     // 16896
#define XD     128
#define YD     128
#define ZD     7
#define NOUT   123            // D_BINS + CO
#define PXB    66             // pixels per k_head block: 256 * 66 == NPIX exactly
#define ABUF   4224           // one A chunk: 32 kp rows x 132 floats
#define WOFF   ABUF           // W chunk follows A chunk in LDS
#define WCHUNK 8192           // one W chunk: 32 kp rows x 256 floats

typedef float v2f __attribute__((ext_vector_type(2)));

// ---------------------------------------------------------------------------
// Double-precision rigid-transform inverse (matches np.linalg.inv to ~1e-15,
// avoiding depth-bin boundary flips downstream).
// ---------------------------------------------------------------------------
__device__ void inv_rigid(const float* __restrict__ M, float* __restrict__ o) {
    double a = M[0], b = M[1], c = M[2], t0 = M[3];
    double d = M[4], e = M[5], f = M[6], t1 = M[7];
    double g = M[8], h = M[9], ii = M[10], t2 = M[11];
    double A00 = e*ii - f*h, A01 = c*h - b*ii, A02 = b*f - c*e;
    double A10 = f*g - d*ii, A11 = a*ii - c*g, A12 = c*d - a*f;
    double A20 = d*h - e*g,  A21 = b*g - a*h,  A22 = a*e - b*d;
    double det = a*A00 + b*A10 + c*A20;
    double inv = 1.0 / det;
    double r00 = A00*inv, r01 = A01*inv, r02 = A02*inv;
    double r10 = A10*inv, r11 = A11*inv, r12 = A12*inv;
    double r20 = A20*inv, r21 = A21*inv, r22 = A22*inv;
    o[0] = (float)r00; o[1] = (float)r01; o[2]  = (float)r02;
    o[3] = (float)(-(r00*t0 + r01*t1 + r02*t2));
    o[4] = (float)r10; o[5] = (float)r11; o[6]  = (float)r12;
    o[7] = (float)(-(r10*t0 + r11*t1 + r12*t2));
    o[8] = (float)r20; o[9] = (float)r21; o[10] = (float)r22;
    o[11] = (float)(-(r20*t0 + r21*t1 + r22*t2));
}

// ---------------------------------------------------------------------------
// Kernel 1: prep. W (123x256) -> wt2, k-pair-interleaved + transposed.
// Unchanged.
// ---------------------------------------------------------------------------
__global__ __launch_bounds__(256) void k_pre(
    const float* __restrict__ wd, const float* __restrict__ c2e,
    float* __restrict__ wt2, float* __restrict__ e2c) {
    const int o = blockIdx.x;   // 0..127
    const int k = threadIdx.x;  // 0..255
    float v = (o < NOUT) ? wd[(size_t)o * CI + k] : 0.f;
    wt2[(size_t)(k >> 1) * 256 + o * 2 + (k & 1)] = v;
    if (blockIdx.x == 0 && k < NB * NC)
        inv_rigid(c2e + k * 16, e2c + k * 12);
}

// ---------------------------------------------------------------------------
// Kernel 2: depth/feat head. NEW this round: W chunk staged into LDS.
// Theory: the wave-uniform wt2 reads were per-lane VMEM (16/k2/wave = 20.5K
// VMEM insts/CU, ~4cyc issue each ~= 34 us of pure VMEM issue). Now W's 32KB
// chunk is reg-prefetched (T14) and ds_written once per kc; the inner loop
// reads it with broadcast ds_read_b128 (8 DS ops/k2) + 1 ds_read_b64 for A.
// A and W are single-buffered (49 KB static LDS); loads for chunk kc+1 are
// issued before compute(kc) and written between two barriers after it.
// FMA order and operand values bit-identical to the 124 us baseline.
// ---------------------------------------------------------------------------
__global__ __launch_bounds__(640) void k_head(
    const float* __restrict__ img, const float* __restrict__ wt2,
    const float* __restrict__ bd, float* __restrict__ depth_out,
    float* __restrict__ feat_ws) {
    __shared__ float smem[ABUF + WCHUNK + PXB];  // A | W ; X[66][132] aliases
    float* S = smem + ABUF + WCHUNK;

    const int tid = threadIdx.x;
    const int wv  = tid >> 6;            // 0..9
    const int ln  = tid & 63;
    const int p0  = blockIdx.x * PXB;
    const bool is_main = (wv < 8);
    const int o0  = __builtin_amdgcn_readfirstlane((is_main ? wv : 0) << 4);
    const int epx = 64 + (wv - 8);       // edge wave's pixel column (64 or 65)

    // ---- A staging address precompute (kc-invariant) ----
    int a_off[7];   // LDS offset within A buffer, -1 = inactive
    int g_off[7];   // img element offset for kc=0 (add kc*64*HW)
#pragma unroll
    for (int it = 0; it < 7; ++it) {
        int idx = tid + it * 640;
        if (idx < 64 * PXB) {
            int kl = idx / PXB, px = idx - kl * PXB;
            int p = p0 + px;
            int bn = p / HW, hw = p - bn * HW;
            a_off[it] = (kl >> 1) * 132 + px * 2 + (kl & 1);
            g_off[it] = (bn * CI + kl) * HW + hw;
        } else {
            a_off[it] = -1;
            g_off[it] = 0;
        }
    }

    v2f acc[16];                          // [o-within-strip] = {even-k, odd-k}
#pragma unroll
    for (int j = 0; j < 16; ++j) acc[j] = (v2f)(0.f);
    v2f acc2a = (v2f)(0.f), acc2b = (v2f)(0.f);

    float  ra[7];
    float4 rw[4];                         // 2048 float4 per W chunk / 640 thr

    // prologue: stage chunk 0 (A + W)
#pragma unroll
    for (int it = 0; it < 7; ++it)
        if (a_off[it] >= 0) ra[it] = img[g_off[it]];
#pragma unroll
    for (int it = 0; it < 4; ++it) {
        int idx = tid + it * 640;
        if (idx < WCHUNK / 4) rw[it] = ((const float4*)wt2)[idx];
    }
#pragma unroll
    for (int it = 0; it < 7; ++it)
        if (a_off[it] >= 0) smem[a_off[it]] = ra[it];
#pragma unroll
    for (int it = 0; it < 4; ++it) {
        int idx = tid + it * 640;
        if (idx < WCHUNK / 4) ((float4*)(smem + WOFF))[idx] = rw[it];
    }
    __syncthreads();

    for (int kc = 0; kc < 4; ++kc) {
        // issue next chunk's loads early (consumed after compute)
        if (kc < 3) {
#pragma unroll
            for (int it = 0; it < 7; ++it)
                if (a_off[it] >= 0)
                    ra[it] = img[g_off[it] + (kc + 1) * 64 * HW];
#pragma unroll
            for (int it = 0; it < 4; ++it) {
                int idx = tid + it * 640;
                if (idx < WCHUNK / 4)
                    rw[it] = ((const float4*)(wt2 + (size_t)(kc + 1) * WCHUNK))[idx];
            }
        }

        if (is_main) {
#pragma unroll 4
            for (int k2 = 0; k2 < 32; ++k2) {
                v2f a = *(const v2f*)(smem + k2 * 132 + ln * 2); // stride-8B: free
                const float* wr = smem + WOFF + k2 * 256 + o0 * 2; // uniform
#pragma unroll
                for (int jj = 0; jj < 8; ++jj) {
                    float4 wq = *(const float4*)(wr + jj * 4);   // b128 broadcast
                    v2f w0 = {wq.x, wq.y};
                    v2f w1 = {wq.z, wq.w};
                    acc[jj * 2]     = __builtin_elementwise_fma(a, w0, acc[jj * 2]);
                    acc[jj * 2 + 1] = __builtin_elementwise_fma(a, w1, acc[jj * 2 + 1]);
                }
            }
        } else {
#pragma unroll 4
            for (int k2 = 0; k2 < 32; ++k2) {
                v2f a = *(const v2f*)(smem + k2 * 132 + epx * 2);  // broadcast
                const float* wr = smem + WOFF + k2 * 256;
                v2f w0 = *(const v2f*)(wr + ln * 2);               // 2-way: free
                v2f w1 = *(const v2f*)(wr + (ln + 64) * 2);
                acc2a = __builtin_elementwise_fma(a, w0, acc2a);
                acc2b = __builtin_elementwise_fma(a, w1, acc2b);
            }
        }
        __syncthreads();   // all reads of A/W(kc) done

        if (kc < 3) {
#pragma unroll
            for (int it = 0; it < 7; ++it)
                if (a_off[it] >= 0) smem[a_off[it]] = ra[it];
#pragma unroll
            for (int it = 0; it < 4; ++it) {
                int idx = tid + it * 640;
                if (idx < WCHUNK / 4) ((float4*)(smem + WOFF))[idx] = rw[it];
            }
            __syncthreads();  // chunk kc+1 visible
        }
    }

    // epilogue into X[66][132]: logits at col o (<59), feat at col o+5 (64..127)
    float* X = smem;   // aliases A+W region (all consumed)
    if (is_main) {
#pragma unroll
        for (int j = 0; j < 16; ++j) {
            int o = o0 + j;
            if (o < NOUT) {
                int col = (o < D_BINS) ? o : o + 5;
                X[ln * 132 + col] = (acc[j].x + acc[j].y) + bd[o];
            }
        }
    } else {
        int o = ln;
        X[epx * 132 + ((o < D_BINS) ? o : o + 5)] = (acc2a.x + acc2a.y) + bd[o];
        o = ln + 64;
        if (o < NOUT)
            X[epx * 132 + ((o < D_BINS) ? o : o + 5)] = (acc2b.x + acc2b.y) + bd[o];
    }
    __syncthreads();

    // feat: X[p][64..127] -> feat_ws[(p0+p)*64 ...], coalesced float4
#pragma unroll
    for (int it = 0; it < 2; ++it) {
        int g = tid + it * 640;            // 66*16 = 1056 float4s
        if (g < PXB * 16) {
            int p = g >> 4, m = g & 15;
            float4 v = *(const float4*)(X + p * 132 + 64 + m * 4);
            *(float4*)(feat_ws + (size_t)(p0 + p) * CO + m * 4) = v;
        }
    }

    // softmax over cols 0..58, one thread per pixel
    if (tid < PXB) {
        float* row = X + tid * 132;
        float m = row[0];
        for (int o = 1; o < D_BINS; ++o) m = fmaxf(m, row[o]);
        float s = 0.f;
        for (int o = 0; o < D_BINS; ++o) {
            float e = __expf(row[o] - m);
            row[o] = e;
            s += e;
        }
        S[tid] = 1.f / s;
    }
    __syncthreads();

    // depth: block region contiguous [p0*59, (p0+66)*59) -> coalesced
    for (int g = tid; g < PXB * D_BINS; g += 640) {
        int p = g / D_BINS;
        int o = g - p * D_BINS;
        depth_out[(size_t)p0 * D_BINS + g] = X[p * 132 + o] * S[p];
    }
}

// ---------------------------------------------------------------------------
// Kernel 3: project voxels, gather depth weight + feat, splat to BEV.
// Round-0 (124 us baseline) version, byte-identical. Per camera n, a
// projection phase computes each (x,z) sample's {hw, depth-weight} ONCE into
// LDS; the accumulate phase broadcasts them to all 4 channel-quarter threads
// which do only their feat gathers + FMAs.
// ---------------------------------------------------------------------------
__global__ __launch_bounds__(256) void k_splat(
    const float* __restrict__ e2c, const float* __restrict__ Kmat,
    const float* __restrict__ depth_g, const float* __restrict__ feat_ws,
    float* __restrict__ bev) {
    __shared__ int   hw_s[ZD][64];
    __shared__ float wgt_s[ZD][64];

    const int tx = threadIdx.x;          // 0..63 -> x
    const int cq = threadIdx.y;          // 0..3  -> channel quarter / z-slice
    const int x = blockIdx.x * 64 + tx;
    const int y = blockIdx.y;
    const int b = blockIdx.z;
    const float wx = (float)x * 0.8f + (-51.2f);
    const float wy = (float)y * 0.8f + (-51.2f);

    float acc[16];
#pragma unroll
    for (int m = 0; m < 16; ++m) acc[m] = 0.f;

    for (int n = 0; n < NC; ++n) {
        const int bn = b * NC + n;
        const float* E = e2c + bn * 12;
        const float* Km = Kmat + bn * 9;
        const float k00 = Km[0], k01 = Km[1], k02 = Km[2];
        const float k10 = Km[3], k11 = Km[4], k12 = Km[5];
        const float e02 = E[2], e12 = E[6], e22 = E[10];
        const float bx0 = E[0] * wx + E[1] * wy + E[3];
        const float bx1 = E[4] * wx + E[5] * wy + E[7];
        const float bx2 = E[8] * wx + E[9] * wy + E[11];

        // ---- projection phase: thread (tx,cq) owns z = cq and cq+4 ----
#pragma unroll
        for (int zz = 0; zz < 2; ++zz) {
            const int z = cq + zz * 4;
            if (z < ZD) {
                const float wz = -2.5f + (float)z;
                const float cx = bx0 + e02 * wz;
                const float cy = bx1 + e12 * wz;
                const float cz = bx2 + e22 * wz;
                const float zs = fmaxf(cz, 0.1f);
                const float rz = 1.0f / zs;         // IEEE divide
                const float xn = cx * rz;
                const float yn = cy * rz;
                const float fu = (k00 * xn + k01 * yn + k02) * 0.0625f;
                const float fv = (k10 * xn + k11 * yn + k12) * 0.0625f;
                const int bin = (int)(cz - 1.0f);   // trunc, matches astype(int32)
                const bool valid = (fu >= 0.f) & (fu < (float)W_IMG) &
                                   (fv >= 0.f) & (fv < (float)H_IMG) &
                                   (cz > 0.5f) & (bin >= 0) & (bin < D_BINS);
                int hw = -1;
                float wgt = 0.f;
                if (valid) {
                    int u = (int)fu;                // valid => in range
                    int v = (int)fv;
                    hw = v * W_IMG + u;
                    wgt = depth_g[((size_t)bn * HW + hw) * D_BINS + bin];
                }
                hw_s[z][tx] = hw;
                wgt_s[z][tx] = wgt;
            }
        }
        __syncthreads();

        // ---- accumulate phase: z ascending (same FMA order as baseline) ----
#pragma unroll
        for (int z = 0; z < ZD; ++z) {
            const int hw = hw_s[z][tx];       // 4 cq threads same addr: broadcast
            if (hw >= 0) {
                const float wgt = wgt_s[z][tx];
                const float4* fp =
                    (const float4*)(feat_ws + ((size_t)bn * HW + hw) * CO + cq * 16);
                float4 f0 = fp[0], f1 = fp[1], f2 = fp[2], f3 = fp[3];
                acc[0]  = fmaf(wgt, f0.x, acc[0]);
                acc[1]  = fmaf(wgt, f0.y, acc[1]);
                acc[2]  = fmaf(wgt, f0.z, acc[2]);
                acc[3]  = fmaf(wgt, f0.w, acc[3]);
                acc[4]  = fmaf(wgt, f1.x, acc[4]);
                acc[5]  = fmaf(wgt, f1.y, acc[5]);
                acc[6]  = fmaf(wgt, f1.z, acc[6]);
                acc[7]  = fmaf(wgt, f1.w, acc[7]);
                acc[8]  = fmaf(wgt, f2.x, acc[8]);
                acc[9]  = fmaf(wgt, f2.y, acc[9]);
                acc[10] = fmaf(wgt, f2.z, acc[10]);
                acc[11] = fmaf(wgt, f2.w, acc[11]);
                acc[12] = fmaf(wgt, f3.x, acc[12]);
                acc[13] = fmaf(wgt, f3.y, acc[13]);
                acc[14] = fmaf(wgt, f3.z, acc[14]);
                acc[15] = fmaf(wgt, f3.w, acc[15]);
            }
        }
        __syncthreads();   // LDS reused next n
    }
    // out[b][c][y][x], c = cq*16 + m; 64 lanes = consecutive x -> coalesced
    float* ob = bev + (((size_t)b * CO + cq * 16) * YD + y) * XD + x;
#pragma unroll
    for (int m = 0; m < 16; ++m) ob[(size_t)m * YD * XD] = acc[m];
}

extern "C" void kernel_launch(void* const* d_in, const int* in_sizes, int n_in,
                              void* d_out, int out_size, void* d_ws, size_t ws_size,
                              hipStream_t stream) {
    const float* img  = (const float*)d_in[0];  // (B,N,256,16,44)
    const float* c2e  = (const float*)d_in[1];  // (B,N,4,4)
    const float* Kmat = (const float*)d_in[2];  // (B,N,3,3)
    const float* wd   = (const float*)d_in[3];  // (123,256)
    const float* bd   = (const float*)d_in[4];  // (123,)
    float* bev = (float*)d_out;                         // (B,64,128,128)
    float* depth_out = bev + (size_t)NB * CO * YD * XD; // (B,N,16,44,59)
    float* feat_ws = (float*)d_ws;                      // NPIX*64 floats
    float* wt2 = feat_ws + (size_t)NPIX * CO;           // 128*256 floats
    float* e2c = wt2 + 128 * 256;                       // 24*12 floats

    k_pre<<<128, 256, 0, stream>>>(wd, c2e, wt2, e2c);
    k_head<<<256, 640, 0, stream>>>(img, wt2, bd, depth_out, feat_ws);
    k_splat<<<dim3(2, YD, NB), dim3(64, 4, 1), 0, stream>>>(e2c, Kmat, depth_out,
                                                            feat_ws, bev);
}

// Round 4
// 121.995 us; speedup vs baseline: 1.1565x; 1.1565x over previous
//
#include <hip/hip_runtime.h>
#include <math.h>

#define D_BINS 59
#define CO     64
#define CI     256
#define NB     4
#define NC     6
#define H_IMG  16
#define W_IMG  44
#define HW     704            // H_IMG * W_IMG
#define NPIX   (NB*NC*HW)     // 16896
#define XD     128
#define YD     128
#define ZD     7
#define NOUT   123            // D_BINS + CO
#define PXB    66             // pixels per k_head block tile
#define THR    384            // k_head threads: 6 waves
#define XW     66             // X row width (64 cols + 2 pad)

typedef float v2f __attribute__((ext_vector_type(2)));

// ---------------------------------------------------------------------------
// Double-precision rigid-transform inverse (matches np.linalg.inv to ~1e-15,
// avoiding depth-bin boundary flips downstream).
// ---------------------------------------------------------------------------
__device__ void inv_rigid(const float* __restrict__ M, float* __restrict__ o) {
    double a = M[0], b = M[1], c = M[2], t0 = M[3];
    double d = M[4], e = M[5], f = M[6], t1 = M[7];
    double g = M[8], h = M[9], ii = M[10], t2 = M[11];
    double A00 = e*ii - f*h, A01 = c*h - b*ii, A02 = b*f - c*e;
    double A10 = f*g - d*ii, A11 = a*ii - c*g, A12 = c*d - a*f;
    double A20 = d*h - e*g,  A21 = b*g - a*h,  A22 = a*e - b*d;
    double det = a*A00 + b*A10 + c*A20;
    double inv = 1.0 / det;
    double r00 = A00*inv, r01 = A01*inv, r02 = A02*inv;
    double r10 = A10*inv, r11 = A11*inv, r12 = A12*inv;
    double r20 = A20*inv, r21 = A21*inv, r22 = A22*inv;
    o[0] = (float)r00; o[1] = (float)r01; o[2]  = (float)r02;
    o[3] = (float)(-(r00*t0 + r01*t1 + r02*t2));
    o[4] = (float)r10; o[5] = (float)r11; o[6]  = (float)r12;
    o[7] = (float)(-(r10*t0 + r11*t1 + r12*t2));
    o[8] = (float)r20; o[9] = (float)r21; o[10] = (float)r22;
    o[11] = (float)(-(r20*t0 + r21*t1 + r22*t2));
}

// ---------------------------------------------------------------------------
// Kernel 1: prep. W (123x256) -> wt2, k-pair-interleaved + transposed:
//   wt2[(k/2)*256 + o*2 + (k&1)], o zero-padded to 128. Unchanged.
// ---------------------------------------------------------------------------
__global__ __launch_bounds__(256) void k_pre(
    const float* __restrict__ wd, const float* __restrict__ c2e,
    float* __restrict__ wt2, float* __restrict__ e2c) {
    const int o = blockIdx.x;   // 0..127
    const int k = threadIdx.x;  // 0..255
    float v = (o < NOUT) ? wd[(size_t)o * CI + k] : 0.f;
    wt2[(size_t)(k >> 1) * 256 + o * 2 + (k & 1)] = v;
    if (blockIdx.x == 0 && k < NB * NC)
        inv_rigid(c2e + k * 16, e2c + k * 12);
}

// ---------------------------------------------------------------------------
// Kernel 2: depth/feat head. NEW this round: OUTPUT-SPLIT, grid (256,2).
// half = blockIdx.y: half 0 computes o in [0,64) (all 59 logits -> softmax +
// depth + feat ch 0..4); half 1 computes o in [64,128) (feat ch 5..63).
// Each block: 6 waves (4 main x o-strip 16, 2 edge px), 34.6 KB LDS ->
// 2 blocks/CU, 12 waves/CU, and TWO INDEPENDENT barrier domains per CU:
// one block's stage/drain overlaps the other's FMA phase (was 1 block/CU
// with all 10 waves draining together at every kc barrier).
// W path back to round-0 form (uniform pointer -> s_load via K$ — the
// round-3 LDS detour regressed 17 us). Per-output FMA order bit-identical.
// ---------------------------------------------------------------------------
__global__ __launch_bounds__(THR) void k_head(
    const float* __restrict__ img, const float* __restrict__ wt2,
    const float* __restrict__ bd, float* __restrict__ depth_out,
    float* __restrict__ feat_ws) {
    __shared__ float A[64 / 2 * 132];        // 4224: 32 kp rows x 132
    __shared__ float X[PXB * XW];            // 4356
    __shared__ float S[PXB];

    const int tid  = threadIdx.x;
    const int wv   = tid >> 6;               // 0..5
    const int ln   = tid & 63;
    const int p0   = blockIdx.x * PXB;
    const int half = blockIdx.y;             // 0 or 1
    const int ob   = half << 6;              // 0 or 64
    const bool is_main = (wv < 4);
    const int o0   = __builtin_amdgcn_readfirstlane(ob + ((is_main ? wv : 0) << 4));
    const int epx  = 64 + (wv - 4);          // edge wave's pixel column

    // ---- A staging addresses (kc-invariant): 4224 = 384 * 11 exactly ----
    int a_off[11];
    int g_off[11];
#pragma unroll
    for (int it = 0; it < 11; ++it) {
        int idx = tid + it * THR;            // < 4224 always
        int kl = idx / PXB, px = idx - kl * PXB;
        int p = p0 + px;
        int bn = p / HW, hw = p - bn * HW;
        a_off[it] = (kl >> 1) * 132 + px * 2 + (kl & 1);
        g_off[it] = (bn * CI + kl) * HW + hw;
    }

    v2f acc[16];                             // main: o-strip of 16
#pragma unroll
    for (int j = 0; j < 16; ++j) acc[j] = (v2f)(0.f);
    v2f acc2 = (v2f)(0.f);                   // edge: o = ob + ln

    for (int kc = 0; kc < 4; ++kc) {
#pragma unroll
        for (int it = 0; it < 11; ++it)
            A[a_off[it]] = img[g_off[it] + kc * 64 * HW];
        __syncthreads();

        if (is_main) {
#pragma unroll 4
            for (int k2 = 0; k2 < 32; ++k2) {
                v2f a = *(const v2f*)(A + k2 * 132 + ln * 2);  // stride-8B: free
                const v2f* w =
                    (const v2f*)(wt2 + (size_t)(kc * 32 + k2) * 256) + o0; // s_load
#pragma unroll
                for (int j = 0; j < 16; ++j)
                    acc[j] = __builtin_elementwise_fma(a, w[j], acc[j]);
            }
        } else {
#pragma unroll 4
            for (int k2 = 0; k2 < 32; ++k2) {
                v2f a = *(const v2f*)(A + k2 * 132 + epx * 2);  // broadcast
                const float* w = wt2 + (size_t)(kc * 32 + k2) * 256;
                v2f w0 = {w[(ob + ln) * 2], w[(ob + ln) * 2 + 1]};
                acc2 = __builtin_elementwise_fma(a, w0, acc2);
            }
        }
        __syncthreads();
    }

    // ---- epilogue into X[66][XW], col = o - ob (0..63) ----
    if (is_main) {
#pragma unroll
        for (int j = 0; j < 16; ++j) {
            int o = o0 + j;
            if (o < NOUT)
                X[ln * XW + (o - ob)] = (acc[j].x + acc[j].y) + bd[o];
        }
    } else {
        int o = ob + ln;
        if (o < NOUT)
            X[epx * XW + ln] = (acc2.x + acc2.y) + bd[o];
    }
    __syncthreads();

    if (half == 0) {
        // feat channels 0..4 (o = 59..63)
        if (tid < PXB * 5) {
            int p = tid / 5, c = tid - p * 5;
            feat_ws[(size_t)(p0 + p) * CO + c] = X[p * XW + 59 + c];
        }
        // softmax over cols 0..58, one thread per pixel
        if (tid < PXB) {
            float* row = X + tid * XW;
            float m = row[0];
            for (int o = 1; o < D_BINS; ++o) m = fmaxf(m, row[o]);
            float s = 0.f;
            for (int o = 0; o < D_BINS; ++o) {
                float e = __expf(row[o] - m);
                row[o] = e;
                s += e;
            }
            S[tid] = 1.f / s;
        }
        __syncthreads();
        // depth: block region contiguous [p0*59, (p0+66)*59) -> coalesced
        for (int g = tid; g < PXB * D_BINS; g += THR) {
            int p = g / D_BINS;
            int o = g - p * D_BINS;
            depth_out[(size_t)p0 * D_BINS + g] = X[p * XW + o] * S[p];
        }
    } else {
        // feat channels 5..63 (o = 64..122 at cols 0..58)
        for (int g = tid; g < PXB * D_BINS; g += THR) {
            int p = g / D_BINS;
            int col = g - p * D_BINS;
            feat_ws[(size_t)(p0 + p) * CO + 5 + col] = X[p * XW + col];
        }
    }
}

// ---------------------------------------------------------------------------
// Kernel 3: project voxels, gather depth weight + feat, splat to BEV.
// Round-0 (124 us baseline) version, byte-identical.
// ---------------------------------------------------------------------------
__global__ __launch_bounds__(256) void k_splat(
    const float* __restrict__ e2c, const float* __restrict__ Kmat,
    const float* __restrict__ depth_g, const float* __restrict__ feat_ws,
    float* __restrict__ bev) {
    __shared__ int   hw_s[ZD][64];
    __shared__ float wgt_s[ZD][64];

    const int tx = threadIdx.x;          // 0..63 -> x
    const int cq = threadIdx.y;          // 0..3  -> channel quarter / z-slice
    const int x = blockIdx.x * 64 + tx;
    const int y = blockIdx.y;
    const int b = blockIdx.z;
    const float wx = (float)x * 0.8f + (-51.2f);
    const float wy = (float)y * 0.8f + (-51.2f);

    float acc[16];
#pragma unroll
    for (int m = 0; m < 16; ++m) acc[m] = 0.f;

    for (int n = 0; n < NC; ++n) {
        const int bn = b * NC + n;
        const float* E = e2c + bn * 12;
        const float* Km = Kmat + bn * 9;
        const float k00 = Km[0], k01 = Km[1], k02 = Km[2];
        const float k10 = Km[3], k11 = Km[4], k12 = Km[5];
        const float e02 = E[2], e12 = E[6], e22 = E[10];
        const float bx0 = E[0] * wx + E[1] * wy + E[3];
        const float bx1 = E[4] * wx + E[5] * wy + E[7];
        const float bx2 = E[8] * wx + E[9] * wy + E[11];

        // ---- projection phase: thread (tx,cq) owns z = cq and cq+4 ----
#pragma unroll
        for (int zz = 0; zz < 2; ++zz) {
            const int z = cq + zz * 4;
            if (z < ZD) {
                const float wz = -2.5f + (float)z;
                const float cx = bx0 + e02 * wz;
                const float cy = bx1 + e12 * wz;
                const float cz = bx2 + e22 * wz;
                const float zs = fmaxf(cz, 0.1f);
                const float rz = 1.0f / zs;         // IEEE divide
                const float xn = cx * rz;
                const float yn = cy * rz;
                const float fu = (k00 * xn + k01 * yn + k02) * 0.0625f;
                const float fv = (k10 * xn + k11 * yn + k12) * 0.0625f;
                const int bin = (int)(cz - 1.0f);   // trunc, matches astype(int32)
                const bool valid = (fu >= 0.f) & (fu < (float)W_IMG) &
                                   (fv >= 0.f) & (fv < (float)H_IMG) &
                                   (cz > 0.5f) & (bin >= 0) & (bin < D_BINS);
                int hw = -1;
                float wgt = 0.f;
                if (valid) {
                    int u = (int)fu;                // valid => in range
                    int v = (int)fv;
                    hw = v * W_IMG + u;
                    wgt = depth_g[((size_t)bn * HW + hw) * D_BINS + bin];
                }
                hw_s[z][tx] = hw;
                wgt_s[z][tx] = wgt;
            }
        }
        __syncthreads();

        // ---- accumulate phase: z ascending (same FMA order as baseline) ----
#pragma unroll
        for (int z = 0; z < ZD; ++z) {
            const int hw = hw_s[z][tx];       // 4 cq threads same addr: broadcast
            if (hw >= 0) {
                const float wgt = wgt_s[z][tx];
                const float4* fp =
                    (const float4*)(feat_ws + ((size_t)bn * HW + hw) * CO + cq * 16);
                float4 f0 = fp[0], f1 = fp[1], f2 = fp[2], f3 = fp[3];
                acc[0]  = fmaf(wgt, f0.x, acc[0]);
                acc[1]  = fmaf(wgt, f0.y, acc[1]);
                acc[2]  = fmaf(wgt, f0.z, acc[2]);
                acc[3]  = fmaf(wgt, f0.w, acc[3]);
                acc[4]  = fmaf(wgt, f1.x, acc[4]);
                acc[5]  = fmaf(wgt, f1.y, acc[5]);
                acc[6]  = fmaf(wgt, f1.z, acc[6]);
                acc[7]  = fmaf(wgt, f1.w, acc[7]);
                acc[8]  = fmaf(wgt, f2.x, acc[8]);
                acc[9]  = fmaf(wgt, f2.y, acc[9]);
                acc[10] = fmaf(wgt, f2.z, acc[10]);
                acc[11] = fmaf(wgt, f2.w, acc[11]);
                acc[12] = fmaf(wgt, f3.x, acc[12]);
                acc[13] = fmaf(wgt, f3.y, acc[13]);
                acc[14] = fmaf(wgt, f3.z, acc[14]);
                acc[15] = fmaf(wgt, f3.w, acc[15]);
            }
        }
        __syncthreads();   // LDS reused next n
    }
    // out[b][c][y][x], c = cq*16 + m; 64 lanes = consecutive x -> coalesced
    float* ob = bev + (((size_t)b * CO + cq * 16) * YD + y) * XD + x;
#pragma unroll
    for (int m = 0; m < 16; ++m) ob[(size_t)m * YD * XD] = acc[m];
}

extern "C" void kernel_launch(void* const* d_in, const int* in_sizes, int n_in,
                              void* d_out, int out_size, void* d_ws, size_t ws_size,
                              hipStream_t stream) {
    const float* img  = (const float*)d_in[0];  // (B,N,256,16,44)
    const float* c2e  = (const float*)d_in[1];  // (B,N,4,4)
    const float* Kmat = (const float*)d_in[2];  // (B,N,3,3)
    const float* wd   = (const float*)d_in[3];  // (123,256)
    const float* bd   = (const float*)d_in[4];  // (123,)
    float* bev = (float*)d_out;                         // (B,64,128,128)
    float* depth_out = bev + (size_t)NB * CO * YD * XD; // (B,N,16,44,59)
    float* feat_ws = (float*)d_ws;                      // NPIX*64 floats
    float* wt2 = feat_ws + (size_t)NPIX * CO;           // 128*256 floats
    float* e2c = wt2 + 128 * 256;                       // 24*12 floats

    k_pre<<<128, 256, 0, stream>>>(wd, c2e, wt2, e2c);
    k_head<<<dim3(256, 2), THR, 0, stream>>>(img, wt2, bd, depth_out, feat_ws);
    k_splat<<<dim3(2, YD, NB), dim3(64, 4, 1), 0, stream>>>(e2c, Kmat, depth_out,
                                                            feat_ws, bev);
}